// Round 6
// baseline (283.385 us; speedup 1.0000x reference)
//
#include <hip/hip_runtime.h>
#include <hip/hip_fp16.h>

#define F 64
#define CHUNK 2048    // edges per chunk (256 thr x 2 int4 x 4)
#define BN 512        // dst nodes per bucket (power of 2)
#define BSHIFT 9
#define CAP 20480     // binfill LDS window slots (80 KB); window ~9.7K expected
// record = (dstLocal<<17)|src : needs n < 2^17 (n=100000 ok)

typedef int v4i __attribute__((ext_vector_type(4)));
typedef float fx4 __attribute__((ext_vector_type(4)));
typedef float v2f __attribute__((ext_vector_type(2)));
typedef _Float16 h8f __attribute__((ext_vector_type(8)));

union FB8 { uint4 u; h8f h; };
union FX4P { fx4 v; v2f p[2]; };

// ============ per-chunk bucket histogram (int4 edge reads, LDS atomics) ============
__global__ __launch_bounds__(256) void k_blkcnt(const int* __restrict__ dst,
                                                int* __restrict__ blkcnt,
                                                int E, int NB, int NBKT) {
    __shared__ int lcnt[256];
    int b = blockIdx.x, t = threadIdx.x;
    lcnt[t] = 0;
    __syncthreads();
    const v4i* d4 = (const v4i*)dst;
    int g0 = (b * CHUNK) >> 2;
    int E4 = E >> 2;   // E divisible by 4 for this problem
#pragma unroll
    for (int k = 0; k < 2; ++k) {
        int gi = g0 + k * 256 + t;
        if (gi < E4) {
            v4i q = __builtin_nontemporal_load(d4 + gi);
            atomicAdd(&lcnt[q.x >> BSHIFT], 1);
            atomicAdd(&lcnt[q.y >> BSHIFT], 1);
            atomicAdd(&lcnt[q.z >> BSHIFT], 1);
            atomicAdd(&lcnt[q.w >> BSHIFT], 1);
        }
    }
    __syncthreads();
    if (t < NBKT) blkcnt[t * NB + b] = lcnt[t];
}

// ============ per-bucket scan over chunk counts -> blkoff, bkttot ============
__global__ __launch_bounds__(256) void k_bktscan(const int* __restrict__ blkcnt,
                                                 int* __restrict__ blkoff,
                                                 int* __restrict__ bkttot, int NB) {
    __shared__ int s[256];
    __shared__ int running;
    int seg = blockIdx.x;
    int t = threadIdx.x;
    if (t == 0) running = 0;
    __syncthreads();
    for (int base = 0; base < NB; base += 256) {
        int i = base + t;
        int v = (i < NB) ? blkcnt[seg * NB + i] : 0;
        s[t] = v;
        __syncthreads();
        for (int off = 1; off < 256; off <<= 1) {
            int x = (t >= off) ? s[t - off] : 0;
            __syncthreads();
            s[t] += x;
            __syncthreads();
        }
        int rbase = running;
        if (i < NB) blkoff[seg * NB + i] = rbase + s[t] - v;
        int ctot = s[255];
        __syncthreads();
        if (t == 0) running = rbase + ctot;
        __syncthreads();
    }
    if (t == 0) bkttot[seg] = running;
}

// exclusive scan of bucket totals (NBKT <= 256) -> sb[0..NBKT]
__global__ void k_sb(const int* __restrict__ bkttot, int* __restrict__ sb, int NBKT) {
    __shared__ int s[256];
    int t = threadIdx.x;
    int v = (t < NBKT) ? bkttot[t] : 0;
    s[t] = v;
    __syncthreads();
    for (int off = 1; off < 256; off <<= 1) {
        int x = (t >= off) ? s[t - off] : 0;
        __syncthreads();
        s[t] += x;
        __syncthreads();
    }
    if (t < NBKT) sb[t] = s[t] - v;          // exclusive
    if (t == NBKT - 1) sb[NBKT] = s[t];      // total
}

// ============ chunk -> bucket-sorted staging, int4 edge reads, 4 B records ============
__global__ __launch_bounds__(256) void k_stage2(const int* __restrict__ src,
                                                const int* __restrict__ dst,
                                                const int* __restrict__ blkoff,
                                                const int* __restrict__ sb,
                                                unsigned* __restrict__ stage,
                                                int E, int NB, int NBKT) {
    __shared__ int lcnt[256];
    __shared__ int lbase[257];
    __shared__ int obase[256];
    __shared__ int s[256];
    __shared__ unsigned rec[CHUNK];
    __shared__ unsigned char binof[CHUNK];
    int b = blockIdx.x, t = threadIdx.x;
    lcnt[t] = 0;
    __syncthreads();
    const v4i* d4 = (const v4i*)dst;
    const v4i* s4 = (const v4i*)src;
    int g0 = (b * CHUNK) >> 2;
    int E4 = E >> 2;
    int myseg[8], myrank[8];
    unsigned myrec[8];
#pragma unroll
    for (int k = 0; k < 2; ++k) {
        int gi = g0 + k * 256 + t;
        bool ok = gi < E4;
        v4i qd = {0, 0, 0, 0}, qs = {0, 0, 0, 0};
        if (ok) {
            qd = __builtin_nontemporal_load(d4 + gi);
            qs = __builtin_nontemporal_load(s4 + gi);
        }
        int dd[4] = {qd.x, qd.y, qd.z, qd.w};
        int ss[4] = {qs.x, qs.y, qs.z, qs.w};
#pragma unroll
        for (int j = 0; j < 4; ++j) {
            int idx = k * 4 + j;
            myseg[idx] = -1;
            if (ok) {
                int sg = dd[j] >> BSHIFT;
                myseg[idx] = sg;
                myrank[idx] = atomicAdd(&lcnt[sg], 1);
                myrec[idx] = ((unsigned)(dd[j] & (BN - 1)) << 17) | (unsigned)ss[j];
            }
        }
    }
    __syncthreads();
    int v = lcnt[t];
    s[t] = v;
    __syncthreads();
    for (int off = 1; off < 256; off <<= 1) {
        int x = (t >= off) ? s[t - off] : 0;
        __syncthreads();
        s[t] += x;
        __syncthreads();
    }
    lbase[t] = s[t] - v;
    if (t == 255) lbase[256] = s[255];
    obase[t] = (t < NBKT) ? sb[t] + blkoff[t * NB + b] : 0;
    __syncthreads();
#pragma unroll
    for (int k = 0; k < 8; ++k) {
        if (myseg[k] >= 0) {
            int p = lbase[myseg[k]] + myrank[k];
            rec[p] = myrec[k];
            binof[p] = (unsigned char)myseg[k];
        }
    }
    __syncthreads();
    int tot = lbase[256];
    for (int j = t; j < tot; j += 256) {
        int sg = binof[j];
        stage[obase[sg] + (j - lbase[sg])] = rec[j];
    }
}

// ============ per-bucket counting: counts + dis + per-bucket padded total ============
__global__ __launch_bounds__(1024) void k_bincount(const unsigned* __restrict__ stage,
                                                   const int* __restrict__ sb,
                                                   int* __restrict__ count,
                                                   float* __restrict__ dis,
                                                   int* __restrict__ padtot, int n) {
    __shared__ int lc[BN];
    int bkt = blockIdx.x, t = threadIdx.x;
    int nb0 = bkt << BSHIFT;
    if (t < BN) lc[t] = 0;
    __syncthreads();
    int r0 = sb[bkt], r1 = sb[bkt + 1];
    for (int j = r0 + t; j < r1; j += 1024) {
        unsigned r = stage[j];
        atomicAdd(&lc[r >> 17], 1);
    }
    __syncthreads();
    int pv = 0;
    if (t < BN) {
        int node = nb0 + t;
        int cv = lc[t];
        if (node < n) {
            count[node] = cv;
            dis[node] = rsqrtf((float)(cv + 1));
            pv = (cv + 3) & ~3;
        }
    }
    __syncthreads();
    if (t < BN) lc[t] = pv;
    __syncthreads();
    for (int off = 256; off > 0; off >>= 1) {
        if (t < off) lc[t] += lc[t + off];
        __syncthreads();
    }
    if (t == 0) padtot[bkt] = lc[0];
}

// scan of per-bucket padded totals -> rbase[0..NBKT]; also row_start[n] = total
__global__ void k_sb2(const int* __restrict__ padtot, int* __restrict__ rbase,
                      int* __restrict__ row_start, int NBKT, int n) {
    __shared__ int s[256];
    int t = threadIdx.x;
    int v = (t < NBKT) ? padtot[t] : 0;
    s[t] = v;
    __syncthreads();
    for (int off = 1; off < 256; off <<= 1) {
        int x = (t >= off) ? s[t - off] : 0;
        __syncthreads();
        s[t] += x;
        __syncthreads();
    }
    if (t < NBKT) rbase[t] = s[t] - v;
    if (t == NBKT - 1) { rbase[NBKT] = s[t]; row_start[n] = s[t]; }
}

// ============ per-bucket fill: local row_start scan + LDS window + coalesced commit ============
__global__ __launch_bounds__(512) void k_binfill(const unsigned* __restrict__ stage,
                                                 const int* __restrict__ sb,
                                                 const int* __restrict__ count,
                                                 const int* __restrict__ rbase,
                                                 int* __restrict__ row_start,
                                                 int* __restrict__ csr, int n) {
    __shared__ int lcur[BN];
    __shared__ int sc[BN];
    __shared__ int buf[CAP];
    int bkt = blockIdx.x, t = threadIdx.x;   // 512 threads, one per bucket node
    int nb0 = bkt << BSHIFT;
    int node = nb0 + t;
    int pv = (node < n) ? ((count[node] + 3) & ~3) : 0;
    sc[t] = pv;
    __syncthreads();
    for (int off = 1; off < BN; off <<= 1) {
        int x = (t >= off) ? sc[t - off] : 0;
        __syncthreads();
        sc[t] += x;
        __syncthreads();
    }
    int excl = sc[t] - pv;
    int w0 = rbase[bkt];
    int wlen = sc[BN - 1];
    lcur[t] = excl;                       // local cursor (bucket-relative)
    if (node < n) row_start[node] = w0 + excl;
    for (int j = t; j < wlen && j < CAP; j += 512) buf[j] = n;   // pad value
    __syncthreads();
    int r0 = sb[bkt], r1 = sb[bkt + 1];
    for (int j = r0 + t; j < r1; j += 512) {
        unsigned r = stage[j];
        int p = atomicAdd(&lcur[r >> 17], 1);
        if (p < CAP) buf[p] = (int)(r & 0x1FFFFu);
    }
    __syncthreads();
    for (int j = t; j < wlen && j < CAP; j += 512) csr[w0 + j] = buf[j];
}

// ============ hs0 = fp16(dis*x), vectorized; zero row n of BOTH buffers ============
__global__ void k_prep(const float4* __restrict__ x4, const float* __restrict__ dis,
                       uint2* __restrict__ hs, uint2* __restrict__ hs2, int n) {
    int i = blockIdx.x * blockDim.x + threadIdx.x;
    int tot = (n + 1) * 16;
    if (i < tot) {
        int row = i >> 4;
        float dv = 0.0f;
        float4 v = make_float4(0.f, 0.f, 0.f, 0.f);
        if (row < n) { dv = dis[row]; v = x4[i]; }
        __half2 h01 = __floats2half2_rn(dv * v.x, dv * v.y);
        __half2 h23 = __floats2half2_rn(dv * v.z, dv * v.w);
        uint2 u;
        u.x = *(unsigned*)&h01;
        u.y = *(unsigned*)&h23;
        hs[i] = u;
    } else if (i < tot + 16) {
        hs2[(size_t)n * 16 + (i - tot)] = make_uint2(0u, 0u);
    }
}

// ============ MFMA aggregation + exact f32 transform — 8 waves/block, depth-2 prefetch ============
// r5 post-mortem: conflicts were benign 2-way writes; real limiter = concurrency
// (Occupancy 29% ~ 2.3 blocks/CU) x latency (gather ~450cyc L3 + LDS chain).
// This round: (1) 512-thread blocks (8 waves, 32KB LDS) -> more resident waves;
// (2) depth-2 gather prefetch (G/H reg sets, unroll-by-2 loop) -> loads issued
// ~2 batch-times (~500cyc) before consumption. Per-wave structure unchanged:
// [f][q] X16 tile, q XOR-swizzle (read 2-way), staircase A, 16x16x32 MFMA,
// exact f32 pk-fma transform. No __syncthreads; per-wave 4KB LDS slice.
__global__ __launch_bounds__(512) void k_layer(const __half* __restrict__ hin,
        const float* __restrict__ W, const float* __restrict__ b,
        const int* __restrict__ row_start, const int* __restrict__ csr,
        const float* __restrict__ dis, __half* __restrict__ hout,
        int n, int scale_out) {
    __shared__ char lds_all[32768];
    int tid = threadIdx.x;
    int lane = tid & 63;
    int wv = tid >> 6;                       // 0..7
    int r0 = (blockIdx.x * 8 + wv) << 4;
    if (r0 >= n) return;
    char* myLds = lds_all + (wv << 12);
    unsigned short* X16 = (unsigned short*)myLds;    // [64 f][32 q] halves, q XOR-swz
    const uint4* h4 = (const uint4*)hin;             // rows = 8 x uint4

    int r_  = lane & 15;
    int g4  = lane >> 4;
    int q32 = lane >> 1;     // neighbor slot within batch (0..31)
    int c2  = lane & 1;      // feature half-row: [32*c2, 32*c2+32)

    int lo = row_start[r0 + r_];
    int hi = row_start[r0 + r_ + 1];
    int s0 = __shfl(lo, 0);
    int s4 = __shfl(hi, 15);
    int NBb = (s4 - s0 + 31) >> 5;      // 32-slot batches; batch NBb = self
    unsigned deg = (unsigned)(hi - lo);

    fx4 acc0 = {0.f, 0.f, 0.f, 0.f};
    fx4 acc1 = acc0, acc2 = acc0, acc3 = acc0;

    auto getnode = [&](int i) -> int {
        if (i < NBb) {
            int slot = s0 + (i << 5) + q32;
            int nd = csr[slot];                 // in-bounds (cap slack); value clamped
            return (slot < s4) ? nd : n;
        }
        return (q32 < 16) ? (r0 + q32) : n;     // self batch (q>=16 -> zero row)
    };

    // swizzled q per chunk-half pair: halves h of a PUT use XOR 8*(h>>1)
    int q0 = q32;
    int q1 = q32 ^ 8;
    int q2 = q32 ^ 16;
    int q3 = q32 ^ 24;
    // B-frag read base: f=16S+r_, q=8*g4+j -> swizzled g4 ^ ((r_>>1)&3)
    const char* rb = myLds + ((r_ << 6) + ((g4 ^ ((r_ >> 1) & 3)) << 4));

#define PUT1(J, GG) { \
    unsigned short* p = X16 + ((fb + 8 * (J)) << 5); \
    p[q0]       = (unsigned short)(GG.x); \
    p[32 + q0]  = (unsigned short)(GG.x >> 16); \
    p[64 + q1]  = (unsigned short)(GG.y); \
    p[96 + q1]  = (unsigned short)(GG.y >> 16); \
    p[128 + q2] = (unsigned short)(GG.z); \
    p[160 + q2] = (unsigned short)(GG.z >> 16); \
    p[192 + q3] = (unsigned short)(GG.w); \
    p[224 + q3] = (unsigned short)(GG.w >> 16); \
}

#define SMFMA(TT) { \
    unsigned w[4]; \
    if ((TT) < NBb) { \
        unsigned u0 = (unsigned)(s0 + ((TT) << 5) + (g4 << 3)) - (unsigned)lo; \
        w[0] = ((u0     ) < deg ? 0x3C00u : 0u) | ((u0 + 1u) < deg ? 0x3C000000u : 0u); \
        w[1] = ((u0 + 2u) < deg ? 0x3C00u : 0u) | ((u0 + 3u) < deg ? 0x3C000000u : 0u); \
        w[2] = ((u0 + 4u) < deg ? 0x3C00u : 0u) | ((u0 + 5u) < deg ? 0x3C000000u : 0u); \
        w[3] = ((u0 + 6u) < deg ? 0x3C00u : 0u) | ((u0 + 7u) < deg ? 0x3C000000u : 0u); \
    } else { \
        int k0 = g4 << 3; \
        w[0] = ((k0    ) == r_ ? 0x3C00u : 0u) | ((k0 + 1) == r_ ? 0x3C000000u : 0u); \
        w[1] = ((k0 + 2) == r_ ? 0x3C00u : 0u) | ((k0 + 3) == r_ ? 0x3C000000u : 0u); \
        w[2] = ((k0 + 4) == r_ ? 0x3C00u : 0u) | ((k0 + 5) == r_ ? 0x3C000000u : 0u); \
        w[3] = ((k0 + 6) == r_ ? 0x3C00u : 0u) | ((k0 + 7) == r_ ? 0x3C000000u : 0u); \
    } \
    FB8 af; af.u = make_uint4(w[0], w[1], w[2], w[3]); \
    FB8 b0_, b1_, b2_, b3_; \
    b0_.u = *(const uint4*)(rb); \
    b1_.u = *(const uint4*)(rb + 1024); \
    b2_.u = *(const uint4*)(rb + 2048); \
    b3_.u = *(const uint4*)(rb + 3072); \
    acc0 = __builtin_amdgcn_mfma_f32_16x16x32_f16(af.h, b0_.h, acc0, 0, 0, 0); \
    acc1 = __builtin_amdgcn_mfma_f32_16x16x32_f16(af.h, b1_.h, acc1, 0, 0, 0); \
    acc2 = __builtin_amdgcn_mfma_f32_16x16x32_f16(af.h, b2_.h, acc2, 0, 0, 0); \
    acc3 = __builtin_amdgcn_mfma_f32_16x16x32_f16(af.h, b3_.h, acc3, 0, 0, 0); \
}

    // depth-2 prefetch: G holds batch t, H holds batch t+1; loads issued 2 ahead
    uint4 G0, G1, G2, G3, H0, H1, H2, H3;
    int nx;
    {
        int a0 = getnode(0);
        int ba = a0 * 8 + c2 * 4;
        G0 = h4[ba]; G1 = h4[ba + 1]; G2 = h4[ba + 2]; G3 = h4[ba + 3];
        int a1 = getnode(1);
        int bb = a1 * 8 + c2 * 4;
        H0 = h4[bb]; H1 = h4[bb + 1]; H2 = h4[bb + 2]; H3 = h4[bb + 3];
        nx = getnode(2);
    }

    for (int t = 0; ; t += 2) {
        { int fb = c2 << 5; PUT1(0, G0) PUT1(1, G1) PUT1(2, G2) PUT1(3, G3) }
        { int bb = nx * 8 + c2 * 4;
          G0 = h4[bb]; G1 = h4[bb + 1]; G2 = h4[bb + 2]; G3 = h4[bb + 3];
          nx = getnode(t + 3); }
        SMFMA(t)
        if (t + 1 > NBb) break;
        { int fb = c2 << 5; PUT1(0, H0) PUT1(1, H1) PUT1(2, H2) PUT1(3, H3) }
        { int bb = nx * 8 + c2 * 4;
          H0 = h4[bb]; H1 = h4[bb + 1]; H2 = h4[bb + 2]; H3 = h4[bb + 3];
          nx = getnode(t + 4); }
        SMFMA(t + 1)
        if (t + 2 > NBb) break;
    }
#undef PUT1
#undef SMFMA

    // ---- dump acc (f32, exact) to T[64 f][16 r]; lane holds D[4g4+v][16S+r_] ----
    float* T = (float*)myLds;
#define TSTORE(S, A) { \
    int fb_ = ((16 * (S) + r_) << 4) + (g4 << 2); \
    *(fx4*)(T + fb_) = A; }
    TSTORE(0, acc0) TSTORE(1, acc1) TSTORE(2, acc2) TSTORE(3, acc3)
#undef TSTORE

    // ---- exact f32 transform (pk-fma): lane = output column o, 16 rows ----
    float bb_ = b[lane];
    v2f yv2[8];
#pragma unroll
    for (int k = 0; k < 8; ++k) { yv2[k].x = 0.f; yv2[k].y = 0.f; }
    const float* Wp = W + lane;
#pragma unroll 4
    for (int f = 0; f < 64; ++f) {
        float w = Wp[f << 6];                   // W[f][lane], coalesced
        v2f wv; wv.x = w; wv.y = w;
        const float* Tf = T + (f << 4);
        FX4P d0, d1, d2, d3;
        d0.v = *(const fx4*)(Tf);               // uniform addr -> LDS broadcast
        d1.v = *(const fx4*)(Tf + 4);
        d2.v = *(const fx4*)(Tf + 8);
        d3.v = *(const fx4*)(Tf + 12);
        yv2[0] += d0.p[0] * wv;  yv2[1] += d0.p[1] * wv;
        yv2[2] += d1.p[0] * wv;  yv2[3] += d1.p[1] * wv;
        yv2[4] += d2.p[0] * wv;  yv2[5] += d2.p[1] * wv;
        yv2[6] += d3.p[0] * wv;  yv2[7] += d3.p[1] * wv;
    }

#pragma unroll
    for (int r = 0; r < 16; ++r) {
        float yvr = (r & 1) ? yv2[r >> 1].y : yv2[r >> 1].x;
        float dd = dis[r0 + r];
        float y = fmaxf(yvr * dd + bb_, 0.f);
        if (scale_out) y *= dd;
        hout[((size_t)(r0 + r) << 6) + lane] = __float2half(y);
    }
}

// ============ final 64->8 linear (fp16 input, fp32 math/out) ============
__global__ __launch_bounds__(256) void k_final(const __half* __restrict__ h,
                                               const float* __restrict__ Wl,
                                               const float* __restrict__ bl,
                                               float* __restrict__ out, int n) {
    __shared__ float Ws[F * 8];
    __shared__ float bs[8];
    int tid = threadIdx.x;
    Ws[tid] = Wl[tid];
    Ws[tid + 256] = Wl[tid + 256];
    if (tid < 8) bs[tid] = bl[tid];
    __syncthreads();
    int idx = blockIdx.x * 256 + tid;
    if (idx >= n * 8) return;
    int row = idx >> 3;
    int o = idx & 7;
    const __half* hr = h + (size_t)row * F;
    float acc = bs[o];
#pragma unroll
    for (int k = 0; k < F; ++k) acc = fmaf(__half2float(hr[k]), Ws[k * 8 + o], acc);
    out[idx] = acc;
}

extern "C" void kernel_launch(void* const* d_in, const int* in_sizes, int n_in,
                              void* d_out, int out_size, void* d_ws, size_t ws_size,
                              hipStream_t stream) {
    const float* x  = (const float*)d_in[0];
    const int*   ei = (const int*)d_in[1];
    const float* W1 = (const float*)d_in[2];
    const float* b1 = (const float*)d_in[3];
    const float* W2 = (const float*)d_in[4];
    const float* b2 = (const float*)d_in[5];
    const float* W3 = (const float*)d_in[6];
    const float* b3 = (const float*)d_in[7];
    const float* Wl = (const float*)d_in[8];
    const float* bl = (const float*)d_in[9];
    float* out = (float*)d_out;

    int n = in_sizes[0] / F;   // 100000 (n % 16 == 0, n < 2^17)
    int E = in_sizes[1] / 2;   // 1600000 (divisible by 4)
    const int* src = ei;
    const int* dst = ei + E;

    int np   = (n + 256) & ~255;              // >= n+1, multiple of 256
    int cap  = E + 3 * n + 64;                // worst-case pad-4 CSR size
    int NB   = (E + CHUNK - 1) / CHUNK;       // 782 chunks
    int NBKT = (n + BN - 1) >> BSHIFT;        // 196 buckets (<=256)

    // workspace layout (~42 MB)
    int*      count     = (int*)d_ws;
    int*      row_start = count + np;
    int*      blkcnt    = row_start + np;       // NBKT*NB (<256*NB)
    int*      blkoff    = blkcnt + 256 * NB;
    int*      bkttot    = blkoff + 256 * NB;    // 256
    int*      sb        = bkttot + 256;         // 257 -> pad 272
    int*      padtot    = sb + 272;             // 256
    int*      rbase     = padtot + 256;         // 257 -> pad 272
    float*    dis       = (float*)(rbase + 272);
    unsigned* stage     = (unsigned*)(dis + np);  // E records (4 B each)
    int*      csr       = (int*)(stage + ((E + 3) & ~3));
    __half*   buf1      = (__half*)(csr + ((cap + 3) & ~3));
    __half*   buf2      = buf1 + (size_t)(n + 1) * F;

    // ---- bucket histogram (one dst pass; NO global atomics; int4 reads) ----
    k_blkcnt<<<NB, 256, 0, stream>>>(dst, blkcnt, E, NB, NBKT);

    // ---- bucket-sorted staging (4 B records; int4 edge reads) ----
    k_bktscan<<<NBKT, 256, 0, stream>>>(blkcnt, blkoff, bkttot, NB);
    k_sb<<<1, 256, 0, stream>>>(bkttot, sb, NBKT);
    k_stage2<<<NB, 256, 0, stream>>>(src, dst, blkoff, sb, stage, E, NB, NBKT);

    // ---- counts + dis + per-bucket padded totals (fused) ----
    k_bincount<<<NBKT, 1024, 0, stream>>>(stage, sb, count, dis, padtot, n);
    k_sb2<<<1, 256, 0, stream>>>(padtot, rbase, row_start, NBKT, n);

    // ---- coalesced CSR commit + row_start (bucket-local scan) ----
    k_binfill<<<NBKT, 512, 0, stream>>>(stage, sb, count, rbase, row_start, csr, n);

    // ---- hs0 = fp16(dis*x), vectorized; zero row n of buf1 AND buf2 ----
    k_prep<<<((n + 1) * 16 + 16 + 255) / 256, 256, 0, stream>>>(
        (const float4*)x, dis, (uint2*)buf1, (uint2*)buf2, n);

    // ---- 3 fused layers (8-wave blocks, depth-2 prefetch MFMA agg) ----
    int nb_l = (n + 127) / 128;   // 8 waves/block, 16 rows/wave
    k_layer<<<nb_l, 512, 0, stream>>>(buf1, W1, b1, row_start, csr, dis, buf2, n, 1);
    k_layer<<<nb_l, 512, 0, stream>>>(buf2, W2, b2, row_start, csr, dis, buf1, n, 1);
    k_layer<<<nb_l, 512, 0, stream>>>(buf1, W3, b3, row_start, csr, dis, buf2, n, 0);

    // ---- final linear ----
    k_final<<<(n * 8 + 255) / 256, 256, 0, stream>>>(buf2, Wl, bl, out, n);
}

// Round 7
// 264.752 us; speedup vs baseline: 1.0704x; 1.0704x over previous
//
#include <hip/hip_runtime.h>
#include <hip/hip_fp16.h>

#define F 64
#define CHUNK 2048    // edges per chunk (256 thr x 2 int4 x 4)
#define BN 512        // dst nodes per bucket (power of 2)
#define BSHIFT 9
#define CAP 20480     // binfill LDS window slots (80 KB); window ~9.7K expected
// record = (dstLocal<<17)|src : needs n < 2^17 (n=100000 ok)

typedef int v4i __attribute__((ext_vector_type(4)));
typedef float fx4 __attribute__((ext_vector_type(4)));
typedef float v2f __attribute__((ext_vector_type(2)));
typedef _Float16 h8f __attribute__((ext_vector_type(8)));

union FB8 { uint4 u; h8f h; };
union FX4P { fx4 v; v2f p[2]; };

// ============ per-chunk bucket histogram (int4 edge reads, LDS atomics) ============
__global__ __launch_bounds__(256) void k_blkcnt(const int* __restrict__ dst,
                                                int* __restrict__ blkcnt,
                                                int E, int NB, int NBKT) {
    __shared__ int lcnt[256];
    int b = blockIdx.x, t = threadIdx.x;
    lcnt[t] = 0;
    __syncthreads();
    const v4i* d4 = (const v4i*)dst;
    int g0 = (b * CHUNK) >> 2;
    int E4 = E >> 2;   // E divisible by 4 for this problem
#pragma unroll
    for (int k = 0; k < 2; ++k) {
        int gi = g0 + k * 256 + t;
        if (gi < E4) {
            v4i q = __builtin_nontemporal_load(d4 + gi);
            atomicAdd(&lcnt[q.x >> BSHIFT], 1);
            atomicAdd(&lcnt[q.y >> BSHIFT], 1);
            atomicAdd(&lcnt[q.z >> BSHIFT], 1);
            atomicAdd(&lcnt[q.w >> BSHIFT], 1);
        }
    }
    __syncthreads();
    if (t < NBKT) blkcnt[t * NB + b] = lcnt[t];
}

// ============ per-bucket scan over chunk counts -> blkoff, bkttot ============
__global__ __launch_bounds__(256) void k_bktscan(const int* __restrict__ blkcnt,
                                                 int* __restrict__ blkoff,
                                                 int* __restrict__ bkttot, int NB) {
    __shared__ int s[256];
    __shared__ int running;
    int seg = blockIdx.x;
    int t = threadIdx.x;
    if (t == 0) running = 0;
    __syncthreads();
    for (int base = 0; base < NB; base += 256) {
        int i = base + t;
        int v = (i < NB) ? blkcnt[seg * NB + i] : 0;
        s[t] = v;
        __syncthreads();
        for (int off = 1; off < 256; off <<= 1) {
            int x = (t >= off) ? s[t - off] : 0;
            __syncthreads();
            s[t] += x;
            __syncthreads();
        }
        int rbase = running;
        if (i < NB) blkoff[seg * NB + i] = rbase + s[t] - v;
        int ctot = s[255];
        __syncthreads();
        if (t == 0) running = rbase + ctot;
        __syncthreads();
    }
    if (t == 0) bkttot[seg] = running;
}

// exclusive scan of bucket totals (NBKT <= 256) -> sb[0..NBKT]
__global__ void k_sb(const int* __restrict__ bkttot, int* __restrict__ sb, int NBKT) {
    __shared__ int s[256];
    int t = threadIdx.x;
    int v = (t < NBKT) ? bkttot[t] : 0;
    s[t] = v;
    __syncthreads();
    for (int off = 1; off < 256; off <<= 1) {
        int x = (t >= off) ? s[t - off] : 0;
        __syncthreads();
        s[t] += x;
        __syncthreads();
    }
    if (t < NBKT) sb[t] = s[t] - v;          // exclusive
    if (t == NBKT - 1) sb[NBKT] = s[t];      // total
}

// ============ chunk -> bucket-sorted staging, int4 edge reads, 4 B records ============
__global__ __launch_bounds__(256) void k_stage2(const int* __restrict__ src,
                                                const int* __restrict__ dst,
                                                const int* __restrict__ blkoff,
                                                const int* __restrict__ sb,
                                                unsigned* __restrict__ stage,
                                                int E, int NB, int NBKT) {
    __shared__ int lcnt[256];
    __shared__ int lbase[257];
    __shared__ int obase[256];
    __shared__ int s[256];
    __shared__ unsigned rec[CHUNK];
    __shared__ unsigned char binof[CHUNK];
    int b = blockIdx.x, t = threadIdx.x;
    lcnt[t] = 0;
    __syncthreads();
    const v4i* d4 = (const v4i*)dst;
    const v4i* s4 = (const v4i*)src;
    int g0 = (b * CHUNK) >> 2;
    int E4 = E >> 2;
    int myseg[8], myrank[8];
    unsigned myrec[8];
#pragma unroll
    for (int k = 0; k < 2; ++k) {
        int gi = g0 + k * 256 + t;
        bool ok = gi < E4;
        v4i qd = {0, 0, 0, 0}, qs = {0, 0, 0, 0};
        if (ok) {
            qd = __builtin_nontemporal_load(d4 + gi);
            qs = __builtin_nontemporal_load(s4 + gi);
        }
        int dd[4] = {qd.x, qd.y, qd.z, qd.w};
        int ss[4] = {qs.x, qs.y, qs.z, qs.w};
#pragma unroll
        for (int j = 0; j < 4; ++j) {
            int idx = k * 4 + j;
            myseg[idx] = -1;
            if (ok) {
                int sg = dd[j] >> BSHIFT;
                myseg[idx] = sg;
                myrank[idx] = atomicAdd(&lcnt[sg], 1);
                myrec[idx] = ((unsigned)(dd[j] & (BN - 1)) << 17) | (unsigned)ss[j];
            }
        }
    }
    __syncthreads();
    int v = lcnt[t];
    s[t] = v;
    __syncthreads();
    for (int off = 1; off < 256; off <<= 1) {
        int x = (t >= off) ? s[t - off] : 0;
        __syncthreads();
        s[t] += x;
        __syncthreads();
    }
    lbase[t] = s[t] - v;
    if (t == 255) lbase[256] = s[255];
    obase[t] = (t < NBKT) ? sb[t] + blkoff[t * NB + b] : 0;
    __syncthreads();
#pragma unroll
    for (int k = 0; k < 8; ++k) {
        if (myseg[k] >= 0) {
            int p = lbase[myseg[k]] + myrank[k];
            rec[p] = myrec[k];
            binof[p] = (unsigned char)myseg[k];
        }
    }
    __syncthreads();
    int tot = lbase[256];
    for (int j = t; j < tot; j += 256) {
        int sg = binof[j];
        stage[obase[sg] + (j - lbase[sg])] = rec[j];
    }
}

// ============ per-bucket counting: counts + dis + per-bucket padded total ============
__global__ __launch_bounds__(1024) void k_bincount(const unsigned* __restrict__ stage,
                                                   const int* __restrict__ sb,
                                                   int* __restrict__ count,
                                                   float* __restrict__ dis,
                                                   int* __restrict__ padtot, int n) {
    __shared__ int lc[BN];
    int bkt = blockIdx.x, t = threadIdx.x;
    int nb0 = bkt << BSHIFT;
    if (t < BN) lc[t] = 0;
    __syncthreads();
    int r0 = sb[bkt], r1 = sb[bkt + 1];
    for (int j = r0 + t; j < r1; j += 1024) {
        unsigned r = stage[j];
        atomicAdd(&lc[r >> 17], 1);
    }
    __syncthreads();
    int pv = 0;
    if (t < BN) {
        int node = nb0 + t;
        int cv = lc[t];
        if (node < n) {
            count[node] = cv;
            dis[node] = rsqrtf((float)(cv + 1));
            pv = (cv + 3) & ~3;
        }
    }
    __syncthreads();
    if (t < BN) lc[t] = pv;
    __syncthreads();
    for (int off = 256; off > 0; off >>= 1) {
        if (t < off) lc[t] += lc[t + off];
        __syncthreads();
    }
    if (t == 0) padtot[bkt] = lc[0];
}

// scan of per-bucket padded totals -> rbase[0..NBKT]; also row_start[n] = total
__global__ void k_sb2(const int* __restrict__ padtot, int* __restrict__ rbase,
                      int* __restrict__ row_start, int NBKT, int n) {
    __shared__ int s[256];
    int t = threadIdx.x;
    int v = (t < NBKT) ? padtot[t] : 0;
    s[t] = v;
    __syncthreads();
    for (int off = 1; off < 256; off <<= 1) {
        int x = (t >= off) ? s[t - off] : 0;
        __syncthreads();
        s[t] += x;
        __syncthreads();
    }
    if (t < NBKT) rbase[t] = s[t] - v;
    if (t == NBKT - 1) { rbase[NBKT] = s[t]; row_start[n] = s[t]; }
}

// ============ per-bucket fill: local row_start scan + LDS window + coalesced commit ============
__global__ __launch_bounds__(512) void k_binfill(const unsigned* __restrict__ stage,
                                                 const int* __restrict__ sb,
                                                 const int* __restrict__ count,
                                                 const int* __restrict__ rbase,
                                                 int* __restrict__ row_start,
                                                 int* __restrict__ csr, int n) {
    __shared__ int lcur[BN];
    __shared__ int sc[BN];
    __shared__ int buf[CAP];
    int bkt = blockIdx.x, t = threadIdx.x;   // 512 threads, one per bucket node
    int nb0 = bkt << BSHIFT;
    int node = nb0 + t;
    int pv = (node < n) ? ((count[node] + 3) & ~3) : 0;
    sc[t] = pv;
    __syncthreads();
    for (int off = 1; off < BN; off <<= 1) {
        int x = (t >= off) ? sc[t - off] : 0;
        __syncthreads();
        sc[t] += x;
        __syncthreads();
    }
    int excl = sc[t] - pv;
    int w0 = rbase[bkt];
    int wlen = sc[BN - 1];
    lcur[t] = excl;                       // local cursor (bucket-relative)
    if (node < n) row_start[node] = w0 + excl;
    for (int j = t; j < wlen && j < CAP; j += 512) buf[j] = n;   // pad value
    __syncthreads();
    int r0 = sb[bkt], r1 = sb[bkt + 1];
    for (int j = r0 + t; j < r1; j += 512) {
        unsigned r = stage[j];
        int p = atomicAdd(&lcur[r >> 17], 1);
        if (p < CAP) buf[p] = (int)(r & 0x1FFFFu);
    }
    __syncthreads();
    for (int j = t; j < wlen && j < CAP; j += 512) csr[w0 + j] = buf[j];
}

// ============ hs0 = fp16(dis*x), vectorized; zero row n of BOTH buffers ============
__global__ void k_prep(const float4* __restrict__ x4, const float* __restrict__ dis,
                       uint2* __restrict__ hs, uint2* __restrict__ hs2, int n) {
    int i = blockIdx.x * blockDim.x + threadIdx.x;
    int tot = (n + 1) * 16;
    if (i < tot) {
        int row = i >> 4;
        float dv = 0.0f;
        float4 v = make_float4(0.f, 0.f, 0.f, 0.f);
        if (row < n) { dv = dis[row]; v = x4[i]; }
        __half2 h01 = __floats2half2_rn(dv * v.x, dv * v.y);
        __half2 h23 = __floats2half2_rn(dv * v.z, dv * v.w);
        uint2 u;
        u.x = *(unsigned*)&h01;
        u.y = *(unsigned*)&h23;
        hs[i] = u;
    } else if (i < tot + 16) {
        hs2[(size_t)n * 16 + (i - tot)] = make_uint2(0u, 0u);
    }
}

// ============ direct-B MFMA aggregation + exact f32 transform ============
// r6 post-mortem: concurrency pinned ~9 waves/CU; per-batch wall ~4.5K cyc vs
// ~250 cyc pipe work -> the LDS round-trip chain (gather->32 ds_write->in-order
// queue->4 ds_read->lgkmcnt->MFMA) was the latency, not bandwidth. This round
// ELIMINATES LDS from the hot loop: B-fragments gathered DIRECTLY from global.
//   B[k=8g4+j][n=16S+r_] = hin[node_k*64 + 16S + r_]: for fixed j the 16 lanes
//   of a group read 32 contiguous bytes of one row (1 cache line) -> each of
//   the 32 short_d16 loads/batch coalesces into 4 segments. node_k via one
//   csr vector-load + 8 __shfl. Double-buffered frag regs + depth-2 node
//   prefetch. MFMA shape/staircase/acc/transform identical to verified r5.
__global__ __launch_bounds__(256) void k_layer(const __half* __restrict__ hin,
        const float* __restrict__ W, const float* __restrict__ b,
        const int* __restrict__ row_start, const int* __restrict__ csr,
        const float* __restrict__ dis, __half* __restrict__ hout,
        int n, int scale_out) {
    __shared__ char lds_all[16384];
    int tid = threadIdx.x;
    int lane = tid & 63;
    int wv = tid >> 6;
    int r0 = (blockIdx.x * 4 + wv) << 4;
    if (r0 >= n) return;
    char* myLds = lds_all + (wv << 12);
    const _Float16* hp = (const _Float16*)hin;

    int r_  = lane & 15;
    int g4  = lane >> 4;
    int l31 = lane & 31;

    int lo = row_start[r0 + r_];
    int hi = row_start[r0 + r_ + 1];
    int s0 = __shfl(lo, 0);
    int s4 = __shfl(hi, 15);
    int NBb = (s4 - s0 + 31) >> 5;      // 32-slot batches; batch NBb = self
    unsigned deg = (unsigned)(hi - lo);

    fx4 acc0 = {0.f, 0.f, 0.f, 0.f};
    fx4 acc1 = acc0, acc2 = acc0, acc3 = acc0;

    // nodes for batch i: lane holds node of slot (l&31)
    auto ldnodes = [&](int i) -> int {
        if (i < NBb) {
            int slot = s0 + (i << 5) + l31;
            int nd = csr[slot];                 // slack in cap; value clamped below
            return (slot < s4) ? nd : n;
        }
        return (l31 < 16) ? (r0 + l31) : n;     // self batch (q>=16 -> zero row)
    };

    // gather B-frags for one batch directly into regs (32 x 2B, 4-segment coalesced)
#define LOADFRAG(F0, F1, F2, F3, NDS) { \
    _Pragma("unroll") \
    for (int j = 0; j < 8; ++j) { \
        int ndj = __shfl((NDS), 8 * g4 + j); \
        const _Float16* rp = hp + (((size_t)(unsigned)ndj) << 6) + r_; \
        F0.h[j] = rp[0]; \
        F1.h[j] = rp[16]; \
        F2.h[j] = rp[32]; \
        F3.h[j] = rp[48]; \
    } \
}

#define SMFMA(TT, F0, F1, F2, F3) { \
    unsigned w[4]; \
    if ((TT) < NBb) { \
        unsigned u0 = (unsigned)(s0 + ((TT) << 5) + (g4 << 3)) - (unsigned)lo; \
        w[0] = ((u0     ) < deg ? 0x3C00u : 0u) | ((u0 + 1u) < deg ? 0x3C000000u : 0u); \
        w[1] = ((u0 + 2u) < deg ? 0x3C00u : 0u) | ((u0 + 3u) < deg ? 0x3C000000u : 0u); \
        w[2] = ((u0 + 4u) < deg ? 0x3C00u : 0u) | ((u0 + 5u) < deg ? 0x3C000000u : 0u); \
        w[3] = ((u0 + 6u) < deg ? 0x3C00u : 0u) | ((u0 + 7u) < deg ? 0x3C000000u : 0u); \
    } else { \
        int k0 = g4 << 3; \
        w[0] = ((k0    ) == r_ ? 0x3C00u : 0u) | ((k0 + 1) == r_ ? 0x3C000000u : 0u); \
        w[1] = ((k0 + 2) == r_ ? 0x3C00u : 0u) | ((k0 + 3) == r_ ? 0x3C000000u : 0u); \
        w[2] = ((k0 + 4) == r_ ? 0x3C00u : 0u) | ((k0 + 5) == r_ ? 0x3C000000u : 0u); \
        w[3] = ((k0 + 6) == r_ ? 0x3C00u : 0u) | ((k0 + 7) == r_ ? 0x3C000000u : 0u); \
    } \
    FB8 af; af.u = make_uint4(w[0], w[1], w[2], w[3]); \
    acc0 = __builtin_amdgcn_mfma_f32_16x16x32_f16(af.h, F0.h, acc0, 0, 0, 0); \
    acc1 = __builtin_amdgcn_mfma_f32_16x16x32_f16(af.h, F1.h, acc1, 0, 0, 0); \
    acc2 = __builtin_amdgcn_mfma_f32_16x16x32_f16(af.h, F2.h, acc2, 0, 0, 0); \
    acc3 = __builtin_amdgcn_mfma_f32_16x16x32_f16(af.h, F3.h, acc3, 0, 0, 0); \
}

    FB8 A0, A1, A2, A3, B0, B1, B2, B3;
    int ndA, ndB;
    {
        int nd0 = ldnodes(0);
        LOADFRAG(A0, A1, A2, A3, nd0)      // B(0)
        ndA = ldnodes(1);                  // nodes(t+1)
        ndB = ldnodes(2);                  // nodes(t+2)
    }

    for (int t = 0; ; t += 2) {
        LOADFRAG(B0, B1, B2, B3, ndA)      // issue B(t+1) gathers
        ndA = ldnodes(t + 3);
        SMFMA(t, A0, A1, A2, A3)
        if (t + 1 > NBb) break;
        LOADFRAG(A0, A1, A2, A3, ndB)      // issue B(t+2) gathers
        ndB = ldnodes(t + 4);
        SMFMA(t + 1, B0, B1, B2, B3)
        if (t + 2 > NBb) break;
    }
#undef LOADFRAG
#undef SMFMA

    // ---- dump acc (f32, exact) to T[64 f][16 r]; lane holds D[4g4+v][16S+r_] ----
    float* T = (float*)myLds;
#define TSTORE(S, A) { \
    int fb_ = ((16 * (S) + r_) << 4) + (g4 << 2); \
    *(fx4*)(T + fb_) = A; }
    TSTORE(0, acc0) TSTORE(1, acc1) TSTORE(2, acc2) TSTORE(3, acc3)
#undef TSTORE

    // ---- exact f32 transform (pk-fma): lane = output column o, 16 rows ----
    float bb_ = b[lane];
    v2f yv2[8];
#pragma unroll
    for (int k = 0; k < 8; ++k) { yv2[k].x = 0.f; yv2[k].y = 0.f; }
    const float* Wp = W + lane;
#pragma unroll 4
    for (int f = 0; f < 64; ++f) {
        float w = Wp[f << 6];                   // W[f][lane], coalesced
        v2f wv; wv.x = w; wv.y = w;
        const float* Tf = T + (f << 4);
        FX4P d0, d1, d2, d3;
        d0.v = *(const fx4*)(Tf);               // uniform addr -> LDS broadcast
        d1.v = *(const fx4*)(Tf + 4);
        d2.v = *(const fx4*)(Tf + 8);
        d3.v = *(const fx4*)(Tf + 12);
        yv2[0] += d0.p[0] * wv;  yv2[1] += d0.p[1] * wv;
        yv2[2] += d1.p[0] * wv;  yv2[3] += d1.p[1] * wv;
        yv2[4] += d2.p[0] * wv;  yv2[5] += d2.p[1] * wv;
        yv2[6] += d3.p[0] * wv;  yv2[7] += d3.p[1] * wv;
    }

#pragma unroll
    for (int r = 0; r < 16; ++r) {
        float yvr = (r & 1) ? yv2[r >> 1].y : yv2[r >> 1].x;
        float dd = dis[r0 + r];
        float y = fmaxf(yvr * dd + bb_, 0.f);
        if (scale_out) y *= dd;
        hout[((size_t)(r0 + r) << 6) + lane] = __float2half(y);
    }
}

// ============ final 64->8 linear (fp16 input, fp32 math/out) ============
__global__ __launch_bounds__(256) void k_final(const __half* __restrict__ h,
                                               const float* __restrict__ Wl,
                                               const float* __restrict__ bl,
                                               float* __restrict__ out, int n) {
    __shared__ float Ws[F * 8];
    __shared__ float bs[8];
    int tid = threadIdx.x;
    Ws[tid] = Wl[tid];
    Ws[tid + 256] = Wl[tid + 256];
    if (tid < 8) bs[tid] = bl[tid];
    __syncthreads();
    int idx = blockIdx.x * 256 + tid;
    if (idx >= n * 8) return;
    int row = idx >> 3;
    int o = idx & 7;
    const __half* hr = h + (size_t)row * F;
    float acc = bs[o];
#pragma unroll
    for (int k = 0; k < F; ++k) acc = fmaf(__half2float(hr[k]), Ws[k * 8 + o], acc);
    out[idx] = acc;
}

extern "C" void kernel_launch(void* const* d_in, const int* in_sizes, int n_in,
                              void* d_out, int out_size, void* d_ws, size_t ws_size,
                              hipStream_t stream) {
    const float* x  = (const float*)d_in[0];
    const int*   ei = (const int*)d_in[1];
    const float* W1 = (const float*)d_in[2];
    const float* b1 = (const float*)d_in[3];
    const float* W2 = (const float*)d_in[4];
    const float* b2 = (const float*)d_in[5];
    const float* W3 = (const float*)d_in[6];
    const float* b3 = (const float*)d_in[7];
    const float* Wl = (const float*)d_in[8];
    const float* bl = (const float*)d_in[9];
    float* out = (float*)d_out;

    int n = in_sizes[0] / F;   // 100000 (n % 16 == 0, n < 2^17)
    int E = in_sizes[1] / 2;   // 1600000 (divisible by 4)
    const int* src = ei;
    const int* dst = ei + E;

    int np   = (n + 256) & ~255;              // >= n+1, multiple of 256
    int cap  = E + 3 * n + 64;                // worst-case pad-4 CSR size
    int NB   = (E + CHUNK - 1) / CHUNK;       // 782 chunks
    int NBKT = (n + BN - 1) >> BSHIFT;        // 196 buckets (<=256)

    // workspace layout (~42 MB)
    int*      count     = (int*)d_ws;
    int*      row_start = count + np;
    int*      blkcnt    = row_start + np;       // NBKT*NB (<256*NB)
    int*      blkoff    = blkcnt + 256 * NB;
    int*      bkttot    = blkoff + 256 * NB;    // 256
    int*      sb        = bkttot + 256;         // 257 -> pad 272
    int*      padtot    = sb + 272;             // 256
    int*      rbase     = padtot + 256;         // 257 -> pad 272
    float*    dis       = (float*)(rbase + 272);
    unsigned* stage     = (unsigned*)(dis + np);  // E records (4 B each)
    int*      csr       = (int*)(stage + ((E + 3) & ~3));
    __half*   buf1      = (__half*)(csr + ((cap + 3) & ~3));
    __half*   buf2      = buf1 + (size_t)(n + 1) * F;

    // ---- bucket histogram (one dst pass; NO global atomics; int4 reads) ----
    k_blkcnt<<<NB, 256, 0, stream>>>(dst, blkcnt, E, NB, NBKT);

    // ---- bucket-sorted staging (4 B records; int4 edge reads) ----
    k_bktscan<<<NBKT, 256, 0, stream>>>(blkcnt, blkoff, bkttot, NB);
    k_sb<<<1, 256, 0, stream>>>(bkttot, sb, NBKT);
    k_stage2<<<NB, 256, 0, stream>>>(src, dst, blkoff, sb, stage, E, NB, NBKT);

    // ---- counts + dis + per-bucket padded totals (fused) ----
    k_bincount<<<NBKT, 1024, 0, stream>>>(stage, sb, count, dis, padtot, n);
    k_sb2<<<1, 256, 0, stream>>>(padtot, rbase, row_start, NBKT, n);

    // ---- coalesced CSR commit + row_start (bucket-local scan) ----
    k_binfill<<<NBKT, 512, 0, stream>>>(stage, sb, count, rbase, row_start, csr, n);

    // ---- hs0 = fp16(dis*x), vectorized; zero row n of buf1 AND buf2 ----
    k_prep<<<((n + 1) * 16 + 16 + 255) / 256, 256, 0, stream>>>(
        (const float4*)x, dis, (uint2*)buf1, (uint2*)buf2, n);

    // ---- 3 fused layers (direct-B register gather MFMA agg) ----
    int nb_l = (n + 63) / 64;   // 4 waves/block, 16 rows/wave
    k_layer<<<nb_l, 256, 0, stream>>>(buf1, W1, b1, row_start, csr, dis, buf2, n, 1);
    k_layer<<<nb_l, 256, 0, stream>>>(buf2, W2, b2, row_start, csr, dis, buf1, n, 1);
    k_layer<<<nb_l, 256, 0, stream>>>(buf1, W3, b3, row_start, csr, dis, buf2, n, 0);

    // ---- final linear ----
    k_final<<<(n * 8 + 255) / 256, 256, 0, stream>>>(buf2, Wl, bl, out, n);
}